// Round 4
// baseline (308.836 us; speedup 1.0000x reference)
//
#include <hip/hip_runtime.h>
#include <math.h>

#define Cdim 512
#define CRdim 32
#define Ldim 4096
#define Bdim 64

#define CHUNK_B 16                      // batches per chunk: 16*512*4096*4B = 128 MiB (half of L3)
#define NCHUNK (Bdim / CHUNK_B)         // 4
#define ROWS_PER_CHUNK (CHUNK_B * Cdim) // 8192

typedef float f32x4 __attribute__((ext_vector_type(4)));

// ---------------- Kernel 1: per-(b,c) mean over L (one chunk) ----------------
// Regular loads: allocate the chunk into L2/L3 so the scale pass re-reads it
// from cache (reuse distance is zero intervening bytes).
__global__ __launch_bounds__(256) void se_reduce(const float* __restrict__ x,
                                                 float* __restrict__ mean) {
    const int row = blockIdx.x;               // row within chunk
    const f32x4* xr = reinterpret_cast<const f32x4*>(x + (size_t)row * Ldim);
    const int t = threadIdx.x;                // 256 threads, 1024 float4 per row
    float s = 0.0f;
#pragma unroll
    for (int k = 0; k < 4; ++k) {
        f32x4 v = xr[t + k * 256];
        s += (v.x + v.y) + (v.z + v.w);
    }
#pragma unroll
    for (int off = 32; off > 0; off >>= 1) s += __shfl_down(s, off, 64);
    __shared__ float wsum[4];
    if ((t & 63) == 0) wsum[t >> 6] = s;
    __syncthreads();
    if (t == 0) {
        float tot = (wsum[0] + wsum[1]) + (wsum[2] + wsum[3]);
        mean[row] = tot * (1.0f / Ldim);
    }
}

// ---------------- Kernel 2: tiny MLP (relu -> sigmoid), one chunk ----------------
__global__ __launch_bounds__(512) void se_mlp(const float* __restrict__ mean,
                                              const float* __restrict__ w1,
                                              const float* __restrict__ b1,
                                              const float* __restrict__ w2,
                                              const float* __restrict__ b2,
                                              float* __restrict__ scale) {
    const int b = blockIdx.x;                 // batch within chunk
    const int t = threadIdx.x;                // 512 threads
    __shared__ float m[Cdim];
    __shared__ float h[CRdim];
    m[t] = mean[b * Cdim + t];
    __syncthreads();
    if (t < CRdim) {
        float acc = b1[t];
        const float* w1r = w1 + t * Cdim;
#pragma unroll 8
        for (int c = 0; c < Cdim; ++c) acc = fmaf(m[c], w1r[c], acc);
        h[t] = fmaxf(acc, 0.0f);
    }
    __syncthreads();
    float acc = b2[t];
    const float* w2r = w2 + t * CRdim;
#pragma unroll
    for (int r = 0; r < CRdim; ++r) acc = fmaf(h[r], w2r[r], acc);
    scale[b * Cdim + t] = 1.0f / (1.0f + expf(-acc));
}

// ---------------- Kernel 3: out = x * s[b,c] (one chunk) ----------------
// x-read should hit L2/L3 (chunk just streamed by se_reduce). Non-temporal
// stores keep the output stream from evicting the cached chunk.
__global__ __launch_bounds__(256) void se_scale(const float* __restrict__ x,
                                                const float* __restrict__ scale,
                                                float* __restrict__ out) {
    const int row = blockIdx.x;               // row within chunk
    const float s = scale[row];
    const f32x4* xr = reinterpret_cast<const f32x4*>(x + (size_t)row * Ldim);
    f32x4* orow = reinterpret_cast<f32x4*>(out + (size_t)row * Ldim);
    const int t = threadIdx.x;
#pragma unroll
    for (int k = 0; k < 4; ++k) {
        f32x4 v = xr[t + k * 256];
        v *= s;
        __builtin_nontemporal_store(v, &orow[t + k * 256]);
    }
}

extern "C" void kernel_launch(void* const* d_in, const int* in_sizes, int n_in,
                              void* d_out, int out_size, void* d_ws, size_t ws_size,
                              hipStream_t stream) {
    const float* x  = (const float*)d_in[0];
    const float* w1 = (const float*)d_in[1];
    const float* b1 = (const float*)d_in[2];
    const float* w2 = (const float*)d_in[3];
    const float* b2 = (const float*)d_in[4];
    float* out = (float*)d_out;

    float* mean  = (float*)d_ws;                         // 64*512 floats
    float* scale = mean + (size_t)Bdim * Cdim;

    const size_t chunk_elems = (size_t)ROWS_PER_CHUNK * Ldim;   // 33.5M floats

    for (int ck = 0; ck < NCHUNK; ++ck) {
        const size_t xoff = (size_t)ck * chunk_elems;
        const int roff = ck * ROWS_PER_CHUNK;
        se_reduce<<<ROWS_PER_CHUNK, 256, 0, stream>>>(x + xoff, mean + roff);
        se_mlp<<<CHUNK_B, Cdim, 0, stream>>>(mean + roff, w1, b1, w2, b2, scale + roff);
        se_scale<<<ROWS_PER_CHUNK, 256, 0, stream>>>(x + xoff, scale + roff, out + xoff);
    }
}